// Round 7
// baseline (628.074 us; speedup 1.0000x reference)
//
#include <hip/hip_runtime.h>

#define NS 65536      // B*H*W samples
#define D 64          // embed dim
#define K 1024        // codebook size
#define NEL 4194304   // NS*D

// ---------------------------------------------------------------------------
// Prep: transpose codebook [D,K] -> [K,D], compute ||m_k||^2, zero loss acc.
// R6: 16 blocks (was 4) — block b owns 64 codes; thread = (k-lane, d-quarter),
// loads coalesced across k; norm reduced across the 4 d-quarters via LDS.
// ---------------------------------------------------------------------------
__global__ __launch_bounds__(256) void vq_prep(
    const float* __restrict__ cm,   // [D,K]
    float* __restrict__ ct,         // [K,D]
    float* __restrict__ cnorm,      // [K]
    double* __restrict__ acc)
{
    const int tx = threadIdx.x;
    const int kl = tx & 63;               // k within block
    const int dq = tx >> 6;               // d-quarter 0..3
    const int k  = blockIdx.x * 64 + kl;
    if (blockIdx.x == 0 && tx == 0) *acc = 0.0;

    float v[16];
    float p = 0.f;
#pragma unroll
    for (int j = 0; j < 16; ++j) {
        float t = cm[(dq * 16 + j) * K + k];   // coalesced across k
        v[j] = t;
        p = fmaf(t, t, p);
    }
    float4* dst = (float4*)(ct + (size_t)k * D + dq * 16);
#pragma unroll
    for (int j = 0; j < 4; ++j)
        dst[j] = make_float4(v[4*j], v[4*j+1], v[4*j+2], v[4*j+3]);

    __shared__ float pn[4][64];
    pn[dq][kl] = p;
    __syncthreads();
    if (tx < 64)
        cnorm[blockIdx.x * 64 + tx] = (pn[0][tx] + pn[1][tx]) + (pn[2][tx] + pn[3][tx]);
}

// ---------------------------------------------------------------------------
// Main: register-tiled VALU GEMM. 1024 blocks x 256 threads.
// Block = 64 samples x 1024 codes (4 tiles of 256). Thread = 8 samples x 8
// codes (64 fp32 accumulators).
// R6 vs R5: explicit double-buffered software pipeline in the dc-loop —
// prefetch dc+1's 8 m-fragments (global/L2) and 8 x-fragments (LDS) while
// FMA-ing dc. launch_bounds(256,2): ~222 regs demand needs the 256 cap;
// 2 waves/SIMD is enough because each wave now self-hides latency
// (128 FMAs x 2cyc = 256 cyc per dc >= L2 ~250 cyc).
// ---------------------------------------------------------------------------
__global__ __launch_bounds__(256, 2) void vq_main(
    const float* __restrict__ xin,    // [NS,D]
    const float* __restrict__ ct,     // [K,D]
    const float* __restrict__ cnorm,  // [K]
    float* __restrict__ outq,         // [NS,D]
    float* __restrict__ outidx,       // [NS] (indices as float)
    double* __restrict__ acc_g)
{
    // Region A (16 KB): x_lds[4096] during GEMM; after a barrier, reused as
    // sbv (8 KB) + siv (8 KB); then first 1 KB as red[256].
    __shared__ float smemA[4096];
    __shared__ float cn_lds[1024];    // 4 KB
    __shared__ int   widx[64];

    float* x_lds = smemA;                    // [d][s]
    float* sbv   = smemA;                    // [32][64]
    int*   siv   = (int*)(smemA + 2048);     // [32][64]
    float* red   = smemA;                    // [256]

    const int tx = threadIdx.x;
    const int sg = tx & 7;      // sample octet 0..7  (8 samples each)
    const int kg = tx >> 3;     // code lane 0..31
    const int S0 = blockIdx.x * 64;

    // ---- stage x transposed into LDS [d][s]; stage cnorm ----
    {
        const int s  = tx >> 2;          // 0..63
        const int d0 = (tx & 3) * 16;    // 0/16/32/48
        const float* gp = xin + (size_t)(S0 + s) * D + d0;
        float4 v[4];
#pragma unroll
        for (int q = 0; q < 4; ++q) v[q] = ((const float4*)gp)[q];
#pragma unroll
        for (int q = 0; q < 4; ++q) {
            x_lds[(d0 + 4*q + 0) * 64 + s] = v[q].x;
            x_lds[(d0 + 4*q + 1) * 64 + s] = v[q].y;
            x_lds[(d0 + 4*q + 2) * 64 + s] = v[q].z;
            x_lds[(d0 + 4*q + 3) * 64 + s] = v[q].w;
        }
#pragma unroll
        for (int q = 0; q < 4; ++q) cn_lds[q*256 + tx] = cnorm[q*256 + tx];
    }
    __syncthreads();

    float best[8];
    int   bidx[8];
#pragma unroll
    for (int i = 0; i < 8; ++i) { best[i] = 3.4e38f; bidx[i] = 0; }

    // ---- 4 tiles of 256 codes; thread's codes k = t*256 + j*32 + kg ----
    for (int t = 0; t < 4; ++t) {
        float acc[8][8];
#pragma unroll
        for (int i = 0; i < 8; ++i)
#pragma unroll
            for (int j = 0; j < 8; ++j) acc[i][j] = 0.f;

        const float* mbase = ct + (size_t)(t*256 + kg) * D;

        float4 mf[2][8];   // double-buffered m fragments
        float4 xs[2][8];   // double-buffered x fragments

        // prologue: load dc=0 into buffer 0
#pragma unroll
        for (int j = 0; j < 8; ++j)
            mf[0][j] = *(const float4*)(mbase + j*32*D);
#pragma unroll
        for (int dd = 0; dd < 4; ++dd) {
            const float* xr = x_lds + dd*64 + sg*8;
            xs[0][2*dd]     = *(const float4*)(xr);
            xs[0][2*dd + 1] = *(const float4*)(xr + 4);
        }

#pragma unroll
        for (int dc = 0; dc < 16; ++dc) {
            const int cur = dc & 1;
            const int nxt = cur ^ 1;
            if (dc < 15) {
                // prefetch dc+1 while FMAs below consume dc
#pragma unroll
                for (int j = 0; j < 8; ++j)
                    mf[nxt][j] = *(const float4*)(mbase + j*32*D + (dc+1)*4);
#pragma unroll
                for (int dd = 0; dd < 4; ++dd) {
                    const float* xr = x_lds + ((dc+1)*4 + dd)*64 + sg*8;
                    xs[nxt][2*dd]     = *(const float4*)(xr);
                    xs[nxt][2*dd + 1] = *(const float4*)(xr + 4);
                }
            }
#pragma unroll
            for (int dd = 0; dd < 4; ++dd) {
                const float4 xa = xs[cur][2*dd];
                const float4 xb = xs[cur][2*dd + 1];
#pragma unroll
                for (int j = 0; j < 8; ++j) {
                    const float ms = (dd == 0) ? mf[cur][j].x :
                                     (dd == 1) ? mf[cur][j].y :
                                     (dd == 2) ? mf[cur][j].z : mf[cur][j].w;
                    acc[0][j] = fmaf(xa.x, ms, acc[0][j]);
                    acc[1][j] = fmaf(xa.y, ms, acc[1][j]);
                    acc[2][j] = fmaf(xa.z, ms, acc[2][j]);
                    acc[3][j] = fmaf(xa.w, ms, acc[3][j]);
                    acc[4][j] = fmaf(xb.x, ms, acc[4][j]);
                    acc[5][j] = fmaf(xb.y, ms, acc[5][j]);
                    acc[6][j] = fmaf(xb.z, ms, acc[6][j]);
                    acc[7][j] = fmaf(xb.w, ms, acc[7][j]);
                }
            }
        }
        // distances + running argmin (j ascending => k ascending, strict <)
#pragma unroll
        for (int j = 0; j < 8; ++j) {
            const int k = t*256 + j*32 + kg;
            const float cnv = cn_lds[k];
#pragma unroll
            for (int i = 0; i < 8; ++i) {
                float dist = fmaf(-2.f, acc[i][j], cnv);
                if (dist < best[i]) { best[i] = dist; bidx[i] = k; }
            }
        }
    }

    // ---- combine across the 32 kg-threads per sample ----
    __syncthreads();   // x_lds dead everywhere before sbv/siv overwrite it
#pragma unroll
    for (int i = 0; i < 8; ++i) {
        sbv[kg*64 + sg*8 + i] = best[i];
        siv[kg*64 + sg*8 + i] = bidx[i];
    }
    __syncthreads();
    if (tx < 64) {
        float b = sbv[tx];
        int   w = siv[tx];
#pragma unroll
        for (int p = 1; p < 32; ++p) {
            float bp = sbv[p*64 + tx];
            if (bp < b) { b = bp; w = siv[p*64 + tx]; }
        }
        widx[tx] = w;
    }
    __syncthreads();   // after this, sbv/siv dead -> red may reuse region

    // ---- gather + STE output + loss partial ----
    const int sl = tx >> 2;                 // local sample 0..63
    const int d0 = (tx & 3) * 16;           // dim offset
    const int gs = blockIdx.x * 64 + sl;
    const int w  = widx[sl];
    const float* mq = ct + ((size_t)w << 6) + d0;
    const float* xr = xin + (size_t)gs * D + d0;
    float*       oq = outq + (size_t)gs * D + d0;
    float psum = 0.f;
#pragma unroll
    for (int j = 0; j < 16; j += 4) {
        float4 q  = *(const float4*)(mq + j);
        float4 xv = *(const float4*)(xr + j);
        float4 o;
        float dx = q.x - xv.x, dy = q.y - xv.y, dz = q.z - xv.z, dw = q.w - xv.w;
        o.x = xv.x + dx; o.y = xv.y + dy; o.z = xv.z + dz; o.w = xv.w + dw;
        *(float4*)(oq + j) = o;
        psum = fmaf(dx, dx, psum);
        psum = fmaf(dy, dy, psum);
        psum = fmaf(dz, dz, psum);
        psum = fmaf(dw, dw, psum);
    }

    if (tx < 64)
        outidx[blockIdx.x * 64 + tx] = (float)widx[tx];

    red[tx] = psum;
    __syncthreads();
    for (int st = 128; st > 0; st >>= 1) {
        if (tx < st) red[tx] += red[tx + st];
        __syncthreads();
    }
    if (tx == 0) atomicAdd(acc_g, (double)red[0]);
}

// ---------------------------------------------------------------------------
// Finalize: loss = m + 0.25*m where m = mean((q-x)^2)
// ---------------------------------------------------------------------------
__global__ void vq_finalize(const double* __restrict__ acc,
                            float* __restrict__ loss_out)
{
    float m = (float)(*acc / (double)NEL);
    *loss_out = m + 0.25f * m;
}

extern "C" void kernel_launch(void* const* d_in, const int* in_sizes, int n_in,
                              void* d_out, int out_size, void* d_ws, size_t ws_size,
                              hipStream_t stream) {
    const float* xin = (const float*)d_in[0];   // [16,64,64,64] fp32
    const float* cm  = (const float*)d_in[1];   // [64,1024] fp32

    float* out     = (float*)d_out;
    float* outq    = out;                 // 4194304 floats
    float* outidx  = out + NEL;           // 65536 floats (indices)
    float* outloss = out + NEL + NS;      // 1 float

    float*  ct    = (float*)d_ws;         // 65536 floats = 256 KB
    float*  cnorm = ct + (size_t)K * D;   // 1024 floats
    double* acc   = (double*)(cnorm + K); // 8B-aligned

    vq_prep<<<16, 256, 0, stream>>>(cm, ct, cnorm, acc);
    vq_main<<<1024, 256, 0, stream>>>(xin, ct, cnorm, outq, outidx, acc);
    vq_finalize<<<1, 1, 0, stream>>>(acc, outloss);
}

// Round 8
// 191.632 us; speedup vs baseline: 3.2775x; 3.2775x over previous
//
#include <hip/hip_runtime.h>

#define NS 65536      // B*H*W samples
#define D 64          // embed dim
#define K 1024        // codebook size
#define NEL 4194304   // NS*D

typedef float v2f __attribute__((ext_vector_type(2)));

// ---------------------------------------------------------------------------
// Prep: transpose codebook [D,K] -> [K,D], compute ||m_k||^2, zero loss acc.
// 16 blocks; thread = (k-lane, d-quarter); loads coalesced across k; norm
// reduced across the 4 d-quarters via LDS. (R6's version — keep: the old
// 4-block stride-4KB version cost ~40 µs.)
// ---------------------------------------------------------------------------
__global__ __launch_bounds__(256) void vq_prep(
    const float* __restrict__ cm,   // [D,K]
    float* __restrict__ ct,         // [K,D]
    float* __restrict__ cnorm,      // [K]
    double* __restrict__ acc)
{
    const int tx = threadIdx.x;
    const int kl = tx & 63;               // k within block
    const int dq = tx >> 6;               // d-quarter 0..3
    const int k  = blockIdx.x * 64 + kl;
    if (blockIdx.x == 0 && tx == 0) *acc = 0.0;

    float v[16];
    float p = 0.f;
#pragma unroll
    for (int j = 0; j < 16; ++j) {
        float t = cm[(dq * 16 + j) * K + k];   // coalesced across k
        v[j] = t;
        p = fmaf(t, t, p);
    }
    float4* dst = (float4*)(ct + (size_t)k * D + dq * 16);
#pragma unroll
    for (int j = 0; j < 4; ++j)
        dst[j] = make_float4(v[4*j], v[4*j+1], v[4*j+2], v[4*j+3]);

    __shared__ float pn[4][64];
    pn[dq][kl] = p;
    __syncthreads();
    if (tx < 64)
        cnorm[blockIdx.x * 64 + tx] = (pn[0][tx] + pn[1][tx]) + (pn[2][tx] + pn[3][tx]);
}

// ---------------------------------------------------------------------------
// Main: register-tiled VALU GEMM. 1024 blocks x 256 threads.
// Block = 64 samples x 1024 codes (4 tiles of 256). Thread = 8 samples x 8
// codes (64 fp32 accumulators, held as 4x8 float2 pairs).
// R7 vs R5: FMA core packed as float2 via __builtin_elementwise_fma ->
// v_pk_fma_f32 where available (2 MACs/instr); lowers to 2x v_fma_f32
// otherwise (== R5). R6's explicit double-buffer is REVERTED: dynamic-indexed
// mf[2][8]/xs[2][8] went to scratch (hbm 29MB->1.4GB, 628 µs).
// ---------------------------------------------------------------------------
__global__ __launch_bounds__(256, 3) void vq_main(
    const float* __restrict__ xin,    // [NS,D]
    const float* __restrict__ ct,     // [K,D]
    const float* __restrict__ cnorm,  // [K]
    float* __restrict__ outq,         // [NS,D]
    float* __restrict__ outidx,       // [NS] (indices as float)
    double* __restrict__ acc_g)
{
    // Region A (16 KB): x_lds[4096] during GEMM; after a barrier, reused as
    // sbv (8 KB) + siv (8 KB); then first 1 KB as red[256].
    __shared__ float smemA[4096];
    __shared__ float cn_lds[1024];    // 4 KB
    __shared__ int   widx[64];

    float* x_lds = smemA;                    // [d][s]
    float* sbv   = smemA;                    // [32][64]
    int*   siv   = (int*)(smemA + 2048);     // [32][64]
    float* red   = smemA;                    // [256]

    const int tx = threadIdx.x;
    const int sg = tx & 7;      // sample octet 0..7  (8 samples each)
    const int kg = tx >> 3;     // code lane 0..31
    const int S0 = blockIdx.x * 64;

    // ---- stage x transposed into LDS [d][s]; stage cnorm ----
    {
        const int s  = tx >> 2;          // 0..63
        const int d0 = (tx & 3) * 16;    // 0/16/32/48
        const float* gp = xin + (size_t)(S0 + s) * D + d0;
        float4 v[4];
#pragma unroll
        for (int q = 0; q < 4; ++q) v[q] = ((const float4*)gp)[q];
#pragma unroll
        for (int q = 0; q < 4; ++q) {
            x_lds[(d0 + 4*q + 0) * 64 + s] = v[q].x;
            x_lds[(d0 + 4*q + 1) * 64 + s] = v[q].y;
            x_lds[(d0 + 4*q + 2) * 64 + s] = v[q].z;
            x_lds[(d0 + 4*q + 3) * 64 + s] = v[q].w;
        }
#pragma unroll
        for (int q = 0; q < 4; ++q) cn_lds[q*256 + tx] = cnorm[q*256 + tx];
    }
    __syncthreads();

    float best[8];
    int   bidx[8];
#pragma unroll
    for (int i = 0; i < 8; ++i) { best[i] = 3.4e38f; bidx[i] = 0; }

    // ---- 4 tiles of 256 codes; thread's codes k = t*256 + j*32 + kg ----
    for (int t = 0; t < 4; ++t) {
        v2f accp[4][8];   // [sample-pair][code]
#pragma unroll
        for (int p = 0; p < 4; ++p)
#pragma unroll
            for (int j = 0; j < 8; ++j) accp[p][j] = (v2f){0.f, 0.f};

        const float* mbase = ct + (size_t)(t*256 + kg) * D;

        for (int dc = 0; dc < 16; ++dc) {       // 16 chunks of 4 dims
            // x: 4 dims x 8 samples per dc (8 ds_read_b128 -> 16 v2f)
            v2f xp[4][4];                       // [dd][sample-pair]
#pragma unroll
            for (int dd = 0; dd < 4; ++dd) {
                const float* xr = x_lds + (dc*4 + dd)*64 + sg*8;
                xp[dd][0] = *(const v2f*)(xr);
                xp[dd][1] = *(const v2f*)(xr + 2);
                xp[dd][2] = *(const v2f*)(xr + 4);
                xp[dd][3] = *(const v2f*)(xr + 6);
            }
#pragma unroll
            for (int h = 0; h < 2; ++h) {       // two j-halves of 4 codes
                float4 mf[4];
#pragma unroll
                for (int j = 0; j < 4; ++j)
                    mf[j] = *(const float4*)(mbase + (h*4 + j)*32*D + dc*4);
#pragma unroll
                for (int dd = 0; dd < 4; ++dd) {
#pragma unroll
                    for (int j = 0; j < 4; ++j) {
                        const float ms = (dd == 0) ? mf[j].x :
                                         (dd == 1) ? mf[j].y :
                                         (dd == 2) ? mf[j].z : mf[j].w;
                        const v2f msb = (v2f){ms, ms};
                        const int jj = h*4 + j;
                        accp[0][jj] = __builtin_elementwise_fma(xp[dd][0], msb, accp[0][jj]);
                        accp[1][jj] = __builtin_elementwise_fma(xp[dd][1], msb, accp[1][jj]);
                        accp[2][jj] = __builtin_elementwise_fma(xp[dd][2], msb, accp[2][jj]);
                        accp[3][jj] = __builtin_elementwise_fma(xp[dd][3], msb, accp[3][jj]);
                    }
                }
            }
        }
        // distances + running argmin (j ascending => k ascending, strict <)
#pragma unroll
        for (int j = 0; j < 8; ++j) {
            const int k = t*256 + j*32 + kg;
            const float cnv = cn_lds[k];
#pragma unroll
            for (int p = 0; p < 4; ++p) {
                float d0 = fmaf(-2.f, accp[p][j].x, cnv);
                float d1 = fmaf(-2.f, accp[p][j].y, cnv);
                if (d0 < best[2*p])     { best[2*p]     = d0; bidx[2*p]     = k; }
                if (d1 < best[2*p + 1]) { best[2*p + 1] = d1; bidx[2*p + 1] = k; }
            }
        }
    }

    // ---- combine across the 32 kg-threads per sample ----
    __syncthreads();   // x_lds dead everywhere before sbv/siv overwrite it
#pragma unroll
    for (int i = 0; i < 8; ++i) {
        sbv[kg*64 + sg*8 + i] = best[i];
        siv[kg*64 + sg*8 + i] = bidx[i];
    }
    __syncthreads();
    if (tx < 64) {
        float b = sbv[tx];
        int   w = siv[tx];
#pragma unroll
        for (int p = 1; p < 32; ++p) {
            float bp = sbv[p*64 + tx];
            if (bp < b) { b = bp; w = siv[p*64 + tx]; }
        }
        widx[tx] = w;
    }
    __syncthreads();   // after this, sbv/siv dead -> red may reuse region

    // ---- gather + STE output + loss partial ----
    const int sl = tx >> 2;                 // local sample 0..63
    const int d0 = (tx & 3) * 16;           // dim offset
    const int gs = blockIdx.x * 64 + sl;
    const int w  = widx[sl];
    const float* mq = ct + ((size_t)w << 6) + d0;
    const float* xr = xin + (size_t)gs * D + d0;
    float*       oq = outq + (size_t)gs * D + d0;
    float psum = 0.f;
#pragma unroll
    for (int j = 0; j < 16; j += 4) {
        float4 q  = *(const float4*)(mq + j);
        float4 xv = *(const float4*)(xr + j);
        float4 o;
        float dx = q.x - xv.x, dy = q.y - xv.y, dz = q.z - xv.z, dw = q.w - xv.w;
        o.x = xv.x + dx; o.y = xv.y + dy; o.z = xv.z + dz; o.w = xv.w + dw;
        *(float4*)(oq + j) = o;
        psum = fmaf(dx, dx, psum);
        psum = fmaf(dy, dy, psum);
        psum = fmaf(dz, dz, psum);
        psum = fmaf(dw, dw, psum);
    }

    if (tx < 64)
        outidx[blockIdx.x * 64 + tx] = (float)widx[tx];

    red[tx] = psum;
    __syncthreads();
    for (int st = 128; st > 0; st >>= 1) {
        if (tx < st) red[tx] += red[tx + st];
        __syncthreads();
    }
    if (tx == 0) atomicAdd(acc_g, (double)red[0]);
}

// ---------------------------------------------------------------------------
// Finalize: loss = m + 0.25*m where m = mean((q-x)^2)
// ---------------------------------------------------------------------------
__global__ void vq_finalize(const double* __restrict__ acc,
                            float* __restrict__ loss_out)
{
    float m = (float)(*acc / (double)NEL);
    *loss_out = m + 0.25f * m;
}

extern "C" void kernel_launch(void* const* d_in, const int* in_sizes, int n_in,
                              void* d_out, int out_size, void* d_ws, size_t ws_size,
                              hipStream_t stream) {
    const float* xin = (const float*)d_in[0];   // [16,64,64,64] fp32
    const float* cm  = (const float*)d_in[1];   // [64,1024] fp32

    float* out     = (float*)d_out;
    float* outq    = out;                 // 4194304 floats
    float* outidx  = out + NEL;           // 65536 floats (indices)
    float* outloss = out + NEL + NS;      // 1 float

    float*  ct    = (float*)d_ws;         // 65536 floats = 256 KB
    float*  cnorm = ct + (size_t)K * D;   // 1024 floats
    double* acc   = (double*)(cnorm + K); // 8B-aligned

    vq_prep<<<16, 256, 0, stream>>>(cm, ct, cnorm, acc);
    vq_main<<<1024, 256, 0, stream>>>(xin, ct, cnorm, outq, outidx, acc);
    vq_finalize<<<1, 1, 0, stream>>>(acc, outloss);
}